// Round 1
// baseline (102.780 us; speedup 1.0000x reference)
//
#include <hip/hip_runtime.h>

// RealtimeNgramProcessor: pack sliding windows base-512, table lookup.
// R3 strategy:
//   bigram  -> 1 MB direct-map table (1 random load, -1 = miss)
//   trigram -> open-addressing hash, 2^18 slots, split key/val arrays.
//              ~99.96% of lookups are misses; load factor 0.19 means
//              ~81% of misses resolve on the FIRST probe (empty slot).
//   Both tables share the -1 empty sentinel -> single 2 MB 0xFF memset.
//   Builds fused into one kernel (atomicCAS insert, keys unique).
// Tables rebuilt every launch (ws re-poisoned by harness).

#define TOKEN_VOCAB 512
#define DIRECT2_ENTRIES (TOKEN_VOCAB * TOKEN_VOCAB)  // 262144 (1 MB)
#define LOG_NSLOT3 18
#define NSLOT3 (1 << LOG_NSLOT3)                     // 262144 slots (1 MB keys)
#define MASK3 (NSLOT3 - 1)

__device__ __forceinline__ unsigned hash3(int k) {
    // k < 2^27, uniform-ish; Fibonacci multiplicative hash, top 18 bits.
    return ((unsigned)k * 2654435761u) >> (32 - LOG_NSLOT3);
}

__global__ void build_tables(const int* __restrict__ keys2,
                             const int* __restrict__ vals2, int K2,
                             const int* __restrict__ keys3,
                             const int* __restrict__ vals3, int K3,
                             int* __restrict__ direct2,
                             int* __restrict__ kt3,
                             int* __restrict__ vt3) {
    int i = blockIdx.x * blockDim.x + threadIdx.x;
    if (i < K2) direct2[keys2[i]] = vals2[i];
    if (i < K3) {
        int k = keys3[i];
        unsigned h = hash3(k);
        for (;;) {
            int prev = atomicCAS(&kt3[h], -1, k);
            if (prev == -1) { vt3[h] = vals3[i]; break; }  // keys unique
            h = (h + 1) & MASK3;
        }
    }
}

__global__ void ngram_encode_fast(const int* __restrict__ x,
                                  const int* __restrict__ direct2,
                                  const int* __restrict__ kt3,
                                  const int* __restrict__ vt3,
                                  int* __restrict__ out, int total, int S) {
    int base = (blockIdx.x * blockDim.x + threadIdx.x) * 4;
    if (base >= total) return;
    int s = base & (S - 1);          // row offset; base%4==0 so s>=1 => s>=4
    const int4 cur = *(const int4*)(x + base);
    int tm1 = (s >= 1) ? x[base - 1] : 0;   // left pad 0 at row start
    int tm2 = (s >= 1) ? x[base - 2] : 0;
    int t[6] = {tm2, tm1, cur.x, cur.y, cur.z, cur.w};

    int k3v[4], d2[4], kx[4];
    unsigned h[4];
    #pragma unroll
    for (int j = 0; j < 4; ++j) {
        int k2 = t[j + 1] * TOKEN_VOCAB + t[j + 2];
        int k3 = (t[j] * TOKEN_VOCAB + t[j + 1]) * TOKEN_VOCAB + t[j + 2];
        k3v[j] = k3;
        h[j]   = hash3(k3);
        d2[j]  = direct2[k2];        // 4 independent random loads (MLP)
        kx[j]  = kt3[h[j]];          // 4 independent first probes (MLP)
    }
    int o2[4], o3[4];
    #pragma unroll
    for (int j = 0; j < 4; ++j) {
        o2[j] = (d2[j] < 0) ? 0 : d2[j];
        int v = 0;
        int k = kx[j];
        unsigned hh = h[j];
        while (k != -1) {            // mostly 0-1 iterations (alpha = 0.19)
            if (k == k3v[j]) { v = vt3[hh]; break; }   // hit: rare (~0.04%)
            hh = (hh + 1) & MASK3;
            k = kt3[hh];
        }
        o3[j] = v;
    }
    *(int4*)(out + base)         = make_int4(o2[0], o2[1], o2[2], o2[3]);
    *(int4*)(out + total + base) = make_int4(o3[0], o3[1], o3[2], o3[3]);
}

// Fallback (ws too small): plain binary search per element.
__device__ __forceinline__ int table_lookup(const int* __restrict__ keys,
                                            const int* __restrict__ vals,
                                            int K, int packed) {
    int lo = 0, hi = K;
    while (lo < hi) {
        int mid = (lo + hi) >> 1;
        if (keys[mid] < packed) lo = mid + 1; else hi = mid;
    }
    int pos = lo < (K - 1) ? lo : (K - 1);
    return (keys[pos] == packed) ? vals[pos] : 0;
}

__global__ void ngram_encode_kernel(const int* __restrict__ x,
                                    const int* __restrict__ keys2,
                                    const int* __restrict__ vals2, int K2,
                                    const int* __restrict__ keys3,
                                    const int* __restrict__ vals3, int K3,
                                    int* __restrict__ out, int total, int S) {
    int idx = blockIdx.x * blockDim.x + threadIdx.x;
    if (idx >= total) return;
    int s = idx & (S - 1);
    int t0 = x[idx];
    int t1 = (s >= 1) ? x[idx - 1] : 0;
    int t2 = (s >= 2) ? x[idx - 2] : 0;
    int k2 = t1 * TOKEN_VOCAB + t0;
    int k3 = (t2 * TOKEN_VOCAB + t1) * TOKEN_VOCAB + t0;
    out[idx]         = table_lookup(keys2, vals2, K2, k2);
    out[total + idx] = table_lookup(keys3, vals3, K3, k3);
}

extern "C" void kernel_launch(void* const* d_in, const int* in_sizes, int n_in,
                              void* d_out, int out_size, void* d_ws, size_t ws_size,
                              hipStream_t stream) {
    const int* x     = (const int*)d_in[0];
    const int* keys2 = (const int*)d_in[1];
    const int* vals2 = (const int*)d_in[2];
    const int* keys3 = (const int*)d_in[3];
    const int* vals3 = (const int*)d_in[4];
    int* out = (int*)d_out;

    const int total = in_sizes[0];   // 256*8192
    const int S = 8192;
    const int K2 = in_sizes[1];
    const int K3 = in_sizes[3];

    const size_t ws_needed = (size_t)(DIRECT2_ENTRIES + 2 * NSLOT3) * sizeof(int);
    if (ws_size >= ws_needed) {
        int* direct2 = (int*)d_ws;
        int* kt3     = direct2 + DIRECT2_ENTRIES;
        int* vt3     = kt3 + NSLOT3;

        // One fill covers direct2 + kt3 (both use -1 = empty/miss).
        // vt3 needs no init: only read after a key match.
        hipMemsetAsync(d_ws, 0xFF,
                       (size_t)(DIRECT2_ENTRIES + NSLOT3) * sizeof(int), stream);

        const int kmax = (K2 > K3) ? K2 : K3;
        build_tables<<<(kmax + 255) / 256, 256, 0, stream>>>(
            keys2, vals2, K2, keys3, vals3, K3, direct2, kt3, vt3);

        const int block = 256;
        const int elems = total / 4;
        ngram_encode_fast<<<(elems + block - 1) / block, block, 0, stream>>>(
            x, direct2, kt3, vt3, out, total, S);
    } else {
        const int block = 256;
        ngram_encode_kernel<<<(total + block - 1) / block, block, 0, stream>>>(
            x, keys2, vals2, K2, keys3, vals3, K3, out, total, S);
    }
}

// Round 2
// 97.809 us; speedup vs baseline: 1.0508x; 1.0508x over previous
//
#include <hip/hip_runtime.h>

// RealtimeNgramProcessor: pack sliding windows base-512, table lookup.
// R4 strategy:
//   bigram  -> 1 MB direct-map table (1 random load, -1 = miss)
//   trigram -> open-addressing hash, 2^19 slots (alpha=0.095), split key/val.
//              Probe-1 and probe-2 issued UPFRONT, branchlessly, for all 4
//              elements (probe-2 is slot+1 -> same 64B line 15/16 of time).
//              Residual >=3-probe loop is lane-rare (~1%), wave-rare (~50%).
//   Both tables share the -1 empty sentinel -> single 3 MB 0xFF memset.
//   Builds fused into one kernel (atomicCAS insert, keys unique).
// Diagnostic context: R3 halved scattered loads with ZERO dur change ->
// dur_us appears dominated by harness reset traffic (256 MiB poison fill
// = 42 us @ 80% HBM peak + dozens of restore memsets). This version
// collapses the remaining latency chains; if dur stays ~100 us the
// harness-floor theory is confirmed.

#define TOKEN_VOCAB 512
#define DIRECT2_ENTRIES (TOKEN_VOCAB * TOKEN_VOCAB)  // 262144 (1 MB)
#define LOG_NSLOT3 19
#define NSLOT3 (1 << LOG_NSLOT3)                     // 524288 slots (2 MB keys)
#define MASK3 (NSLOT3 - 1)

__device__ __forceinline__ unsigned hash3(int k) {
    // k < 2^27; Fibonacci multiplicative hash, top LOG_NSLOT3 bits.
    return ((unsigned)k * 2654435761u) >> (32 - LOG_NSLOT3);
}

__global__ void build_tables(const int* __restrict__ keys2,
                             const int* __restrict__ vals2, int K2,
                             const int* __restrict__ keys3,
                             const int* __restrict__ vals3, int K3,
                             int* __restrict__ direct2,
                             int* __restrict__ kt3,
                             int* __restrict__ vt3) {
    int i = blockIdx.x * blockDim.x + threadIdx.x;
    if (i < K2) direct2[keys2[i]] = vals2[i];
    if (i < K3) {
        int k = keys3[i];
        unsigned h = hash3(k);
        for (;;) {
            int prev = atomicCAS(&kt3[h], -1, k);
            if (prev == -1) { vt3[h] = vals3[i]; break; }  // keys unique
            h = (h + 1) & MASK3;
        }
    }
}

__global__ __launch_bounds__(256)
void ngram_encode_fast(const int* __restrict__ x,
                       const int* __restrict__ direct2,
                       const int* __restrict__ kt3,
                       const int* __restrict__ vt3,
                       int* __restrict__ out, int total, int S) {
    int base = (blockIdx.x * blockDim.x + threadIdx.x) * 4;
    if (base >= total) return;
    int s = base & (S - 1);          // row offset; base%4==0 so s>=1 => s>=4
    const int4 cur = *(const int4*)(x + base);
    int tm1 = (s >= 1) ? x[base - 1] : 0;   // left pad 0 at row start
    int tm2 = (s >= 1) ? x[base - 2] : 0;
    int t[6] = {tm2, tm1, cur.x, cur.y, cur.z, cur.w};

    int k3v[4], d2[4], p1[4], p2[4];
    unsigned h[4];
    // Issue ALL primary gathers upfront: 4 direct2 + 4 probe1 + 4 probe2.
    // probe2 (slot+1) shares probe1's cache line with prob 15/16 -> ~free.
    #pragma unroll
    for (int j = 0; j < 4; ++j) {
        int k2 = t[j + 1] * TOKEN_VOCAB + t[j + 2];
        int k3 = (t[j] * TOKEN_VOCAB + t[j + 1]) * TOKEN_VOCAB + t[j + 2];
        k3v[j] = k3;
        h[j]   = hash3(k3);
        d2[j]  = direct2[k2];
        p1[j]  = kt3[h[j]];
        p2[j]  = kt3[(h[j] + 1) & MASK3];
    }
    int o2[4], o3[4];
    #pragma unroll
    for (int j = 0; j < 4; ++j) {
        o2[j] = (d2[j] < 0) ? 0 : d2[j];
        int v = 0;
        if (p1[j] == k3v[j]) {
            v = vt3[h[j]];                       // hit on probe 1 (rare)
        } else if (p1[j] != -1) {
            if (p2[j] == k3v[j]) {
                v = vt3[(h[j] + 1) & MASK3];     // hit on probe 2 (rarer)
            } else if (p2[j] != -1) {
                // >=3 probes: lane prob ~1% at alpha=0.095
                unsigned hh = (h[j] + 2) & MASK3;
                int k = kt3[hh];
                while (k != -1 && k != k3v[j]) { hh = (hh + 1) & MASK3; k = kt3[hh]; }
                if (k == k3v[j]) v = vt3[hh];
            }
        }
        o3[j] = v;
    }
    *(int4*)(out + base)         = make_int4(o2[0], o2[1], o2[2], o2[3]);
    *(int4*)(out + total + base) = make_int4(o3[0], o3[1], o3[2], o3[3]);
}

// Fallback (ws too small): plain binary search per element.
__device__ __forceinline__ int table_lookup(const int* __restrict__ keys,
                                            const int* __restrict__ vals,
                                            int K, int packed) {
    int lo = 0, hi = K;
    while (lo < hi) {
        int mid = (lo + hi) >> 1;
        if (keys[mid] < packed) lo = mid + 1; else hi = mid;
    }
    int pos = lo < (K - 1) ? lo : (K - 1);
    return (keys[pos] == packed) ? vals[pos] : 0;
}

__global__ void ngram_encode_kernel(const int* __restrict__ x,
                                    const int* __restrict__ keys2,
                                    const int* __restrict__ vals2, int K2,
                                    const int* __restrict__ keys3,
                                    const int* __restrict__ vals3, int K3,
                                    int* __restrict__ out, int total, int S) {
    int idx = blockIdx.x * blockDim.x + threadIdx.x;
    if (idx >= total) return;
    int s = idx & (S - 1);
    int t0 = x[idx];
    int t1 = (s >= 1) ? x[idx - 1] : 0;
    int t2 = (s >= 2) ? x[idx - 2] : 0;
    int k2 = t1 * TOKEN_VOCAB + t0;
    int k3 = (t2 * TOKEN_VOCAB + t1) * TOKEN_VOCAB + t0;
    out[idx]         = table_lookup(keys2, vals2, K2, k2);
    out[total + idx] = table_lookup(keys3, vals3, K3, k3);
}

extern "C" void kernel_launch(void* const* d_in, const int* in_sizes, int n_in,
                              void* d_out, int out_size, void* d_ws, size_t ws_size,
                              hipStream_t stream) {
    const int* x     = (const int*)d_in[0];
    const int* keys2 = (const int*)d_in[1];
    const int* vals2 = (const int*)d_in[2];
    const int* keys3 = (const int*)d_in[3];
    const int* vals3 = (const int*)d_in[4];
    int* out = (int*)d_out;

    const int total = in_sizes[0];   // 256*8192
    const int S = 8192;
    const int K2 = in_sizes[1];
    const int K3 = in_sizes[3];

    const size_t ws_needed = (size_t)(DIRECT2_ENTRIES + 2 * NSLOT3) * sizeof(int);
    if (ws_size >= ws_needed) {
        int* direct2 = (int*)d_ws;
        int* kt3     = direct2 + DIRECT2_ENTRIES;
        int* vt3     = kt3 + NSLOT3;

        // One fill covers direct2 + kt3 (both use -1 = empty/miss).
        // vt3 needs no init: only read after a key match.
        hipMemsetAsync(d_ws, 0xFF,
                       (size_t)(DIRECT2_ENTRIES + NSLOT3) * sizeof(int), stream);

        const int kmax = (K2 > K3) ? K2 : K3;
        build_tables<<<(kmax + 255) / 256, 256, 0, stream>>>(
            keys2, vals2, K2, keys3, vals3, K3, direct2, kt3, vt3);

        const int block = 256;
        const int elems = total / 4;
        ngram_encode_fast<<<(elems + block - 1) / block, block, 0, stream>>>(
            x, direct2, kt3, vt3, out, total, S);
    } else {
        const int block = 256;
        ngram_encode_kernel<<<(total + block - 1) / block, block, 0, stream>>>(
            x, keys2, vals2, K2, keys3, vals3, K3, out, total, S);
    }
}